// Round 1
// baseline (699.203 us; speedup 1.0000x reference)
//
#include <hip/hip_runtime.h>
#include <hip/hip_bf16.h>
#include <stdint.h>

// ---------------------------------------------------------------------------
// TernaryLinear: out[b,s,o] = t * sum_i x[b,s,i] * q[o,i]
//   q = ternary(weight) in {-1,0,+1}; t = clip(round(1/(mean|W|+eps)),-1,1)
// Strategy: scalar t folded into epilogue; q and x cast to bf16 (exact for q);
// m97-structure bf16 MFMA GEMM (128x128 tile, BK=64, global_load_lds width 16).
// ---------------------------------------------------------------------------

typedef __bf16 bf16x8 __attribute__((ext_vector_type(8)));
typedef float  f32x4  __attribute__((ext_vector_type(4)));

#define EPS 1e-7f

__device__ __forceinline__ void async_load16(const void* g, void* l) {
    __builtin_amdgcn_global_load_lds(
        (__attribute__((address_space(1))) void*)(const_cast<void*>(g)),
        (__attribute__((address_space(3))) void*)l,
        16, 0, 0);
}

__device__ __forceinline__ unsigned short f2bf_rne(float f) {
    unsigned u = __float_as_uint(f);
    unsigned r = (u + 0x7fffu + ((u >> 16) & 1u)) >> 16;
    return (unsigned short)r;
}

// ---- scalar scale pipeline -------------------------------------------------

__global__ void zero_scalar(float* s) {
    if (threadIdx.x == 0 && blockIdx.x == 0) s[0] = 0.0f;
}

__global__ void absmean_reduce(const float* __restrict__ w, float* __restrict__ sum, int n4) {
    int i = blockIdx.x * blockDim.x + threadIdx.x;
    int stride = gridDim.x * blockDim.x;
    const float4* w4 = (const float4*)w;
    float s = 0.0f;
    for (int j = i; j < n4; j += stride) {
        float4 v = w4[j];
        s += fabsf(v.x) + fabsf(v.y) + fabsf(v.z) + fabsf(v.w);
    }
    #pragma unroll
    for (int off = 32; off > 0; off >>= 1) s += __shfl_down(s, off, 64);
    __shared__ float partial[4];
    int lane = threadIdx.x & 63, wid = threadIdx.x >> 6;
    if (lane == 0) partial[wid] = s;
    __syncthreads();
    if (threadIdx.x == 0)
        atomicAdd(sum, partial[0] + partial[1] + partial[2] + partial[3]);
}

__device__ __forceinline__ float scale_from_sum(const float* sumAbs, float invCount) {
    float mean = sumAbs[0] * invCount;
    float gp = 1.0f / (mean + EPS);
    return fminf(fmaxf(rintf(gp), -1.0f), 1.0f);  // rintf = RNE = half-to-even
}

// ---- conversions -----------------------------------------------------------

__global__ void conv_x_bf16(const float* __restrict__ in, ushort4* __restrict__ out, int n4) {
    int i = blockIdx.x * blockDim.x + threadIdx.x;
    if (i < n4) {
        float4 v = ((const float4*)in)[i];
        ushort4 r;
        r.x = f2bf_rne(v.x); r.y = f2bf_rne(v.y);
        r.z = f2bf_rne(v.z); r.w = f2bf_rne(v.w);
        out[i] = r;
    }
}

__device__ __forceinline__ unsigned short tern_bf16(float w) {
    // +1 -> 0x3F80, -1 -> 0xBF80, 0 -> 0x0000 (exact bf16 bit patterns)
    return (w > 0.5f) ? (unsigned short)0x3F80u
         : ((w < -0.5f) ? (unsigned short)0xBF80u : (unsigned short)0u);
}

__global__ void quant_w_bf16(const float* __restrict__ in, ushort4* __restrict__ out, int n4) {
    int i = blockIdx.x * blockDim.x + threadIdx.x;
    if (i < n4) {
        float4 v = ((const float4*)in)[i];
        ushort4 r;
        r.x = tern_bf16(v.x); r.y = tern_bf16(v.y);
        r.z = tern_bf16(v.z); r.w = tern_bf16(v.w);
        out[i] = r;
    }
}

// ---- bf16 MFMA GEMM (B^T layout: out[m,n] = t * sum_k A[m,k]*B[n,k]) -------

#define BM 128
#define BN 128
#define BK 64

__global__ __launch_bounds__(256) void gemm_bt(
    const __bf16* __restrict__ A,   // [M,K] row-major bf16
    const __bf16* __restrict__ B,   // [N,K] row-major bf16 (ternary)
    float* __restrict__ C,          // [M,N] row-major fp32
    const float* __restrict__ sumAbs,
    int N, int K, float invCount)
{
    __shared__ __bf16 As[BM * BK];
    __shared__ __bf16 Bs[BN * BK];

    const int t    = threadIdx.x;
    const int lane = t & 63;
    const int wid  = t >> 6;
    const int mBase = blockIdx.y * BM;
    const int nBase = blockIdx.x * BN;
    const int wm = (wid >> 1) * 64;   // wave row offset in tile
    const int wn = (wid & 1) * 64;    // wave col offset in tile
    const int lm = lane & 15;
    const int quad = lane >> 4;

    f32x4 acc[4][4] = {};

    const __bf16* gA = A + (size_t)mBase * K;
    const __bf16* gB = B + (size_t)nBase * K;

    // Precompute per-thread staging chunk coords (chunk = 16B = 8 bf16)
    // chunk ch in [0,1024): row = ch>>3, col16 = (ch&7)*8
    for (int k0 = 0; k0 < K; k0 += BK) {
        #pragma unroll
        for (int i = 0; i < 4; ++i) {
            int ch = i * 256 + t;
            int row = ch >> 3, c = (ch & 7) * 8;
            async_load16(gA + (size_t)row * K + k0 + c, &As[ch * 8]);
        }
        #pragma unroll
        for (int i = 0; i < 4; ++i) {
            int ch = i * 256 + t;
            int row = ch >> 3, c = (ch & 7) * 8;
            async_load16(gB + (size_t)row * K + k0 + c, &Bs[ch * 8]);
        }
        __syncthreads();   // drains vmcnt (LDS writes) + barrier

        #pragma unroll
        for (int ks = 0; ks < BK; ks += 32) {
            bf16x8 af[4], bfr[4];
            #pragma unroll
            for (int mt = 0; mt < 4; ++mt)
                af[mt] = *(const bf16x8*)&As[(wm + mt * 16 + lm) * BK + ks + quad * 8];
            #pragma unroll
            for (int nt = 0; nt < 4; ++nt)
                bfr[nt] = *(const bf16x8*)&Bs[(wn + nt * 16 + lm) * BK + ks + quad * 8];
            #pragma unroll
            for (int mt = 0; mt < 4; ++mt)
                #pragma unroll
                for (int nt = 0; nt < 4; ++nt)
                    acc[mt][nt] = __builtin_amdgcn_mfma_f32_16x16x32_bf16(
                        af[mt], bfr[nt], acc[mt][nt], 0, 0, 0);
        }
        __syncthreads();   // all reads done before next stage overwrites LDS
    }

    const float tscale = scale_from_sum(sumAbs, invCount);

    // C/D layout: col = lane&15, row = quad*4 + reg
    #pragma unroll
    for (int mt = 0; mt < 4; ++mt) {
        #pragma unroll
        for (int nt = 0; nt < 4; ++nt) {
            #pragma unroll
            for (int r = 0; r < 4; ++r) {
                int row = mBase + wm + mt * 16 + quad * 4 + r;
                int col = nBase + wn + nt * 16 + lm;
                C[(size_t)row * N + col] = tscale * acc[mt][nt][r];
            }
        }
    }
}

// ---- fallback (ws too small): fp32 tiled GEMM with on-the-fly quantize ----

__global__ void gemm_fallback(const float* __restrict__ x, const float* __restrict__ w,
                              float* __restrict__ out, const float* __restrict__ sumAbs,
                              int N, int K, float invCount)
{
    __shared__ float xs[16][17];
    __shared__ float qs[16][17];
    int tx = threadIdx.x & 15;
    int ty = threadIdx.x >> 4;
    int row = blockIdx.y * 16 + ty;
    int col = blockIdx.x * 16 + tx;
    float acc = 0.0f;
    for (int k0 = 0; k0 < K; k0 += 16) {
        xs[ty][tx] = x[(size_t)row * K + k0 + tx];
        float wv = w[(size_t)(blockIdx.x * 16 + ty) * K + k0 + tx];
        qs[ty][tx] = (wv > 0.5f) ? 1.0f : ((wv < -0.5f) ? -1.0f : 0.0f);
        __syncthreads();
        #pragma unroll
        for (int j = 0; j < 16; ++j) acc += xs[ty][j] * qs[tx][j];
        __syncthreads();
    }
    out[(size_t)row * N + col] = scale_from_sum(sumAbs, invCount) * acc;
}

// ---------------------------------------------------------------------------

extern "C" void kernel_launch(void* const* d_in, const int* in_sizes, int n_in,
                              void* d_out, int out_size, void* d_ws, size_t ws_size,
                              hipStream_t stream) {
    const float* x = (const float*)d_in[0];
    const float* w = (const float*)d_in[1];
    float* out = (float*)d_out;

    const int K = 4096;
    const int M = in_sizes[0] / K;       // 8192
    const int N = in_sizes[1] / K;       // 4096
    const float invCount = 1.0f / (float)(in_sizes[1]);

    float* sumAbs = (float*)d_ws;
    const size_t need = 256 + (size_t)M * K * 2 + (size_t)N * K * 2;

    zero_scalar<<<1, 64, 0, stream>>>(sumAbs);
    absmean_reduce<<<4096, 256, 0, stream>>>(w, sumAbs, in_sizes[1] / 4);

    if (ws_size >= need) {
        __bf16* xb = (__bf16*)((char*)d_ws + 256);
        __bf16* qb = (__bf16*)((char*)d_ws + 256 + (size_t)M * K * 2);

        int xn4 = (M * K) / 4;
        int wn4 = (N * K) / 4;
        conv_x_bf16<<<(xn4 + 255) / 256, 256, 0, stream>>>(x, (ushort4*)xb, xn4);
        quant_w_bf16<<<(wn4 + 255) / 256, 256, 0, stream>>>(w, (ushort4*)qb, wn4);

        dim3 grid(N / BN, M / BM);
        gemm_bt<<<grid, 256, 0, stream>>>(xb, qb, out, sumAbs, N, K, invCount);
    } else {
        dim3 grid(N / 16, M / 16);
        gemm_fallback<<<grid, 256, 0, stream>>>(x, w, out, sumAbs, N, K, invCount);
    }
}

// Round 2
// 570.227 us; speedup vs baseline: 1.2262x; 1.2262x over previous
//
#include <hip/hip_runtime.h>
#include <hip/hip_bf16.h>
#include <stdint.h>

// ---------------------------------------------------------------------------
// TernaryLinear: out[b,s,o] = t * sum_i x[b,s,i] * q[o,i]
//   q = ternary(weight) in {-1,0,+1}; t = clip(round(1/(mean|W|+eps)),-1,1)
// R1: XOR-swizzled LDS layout (kills 1e8 bank-conflict cycles), prep fused
//     to 3 dispatches (quant+absmean partials, x->bf16, gemm w/ epilogue
//     partial-reduction for the scalar scale).
// ---------------------------------------------------------------------------

typedef __bf16 bf16x8 __attribute__((ext_vector_type(8)));
typedef float  f32x4  __attribute__((ext_vector_type(4)));

#define EPS 1e-7f
#define NPART 4096   // partial-sum slots (quant kernel grid size)

__device__ __forceinline__ void async_load16(const void* g, void* l) {
    __builtin_amdgcn_global_load_lds(
        (__attribute__((address_space(1))) void*)(const_cast<void*>(g)),
        (__attribute__((address_space(3))) void*)l,
        16, 0, 0);
}

__device__ __forceinline__ unsigned short f2bf_rne(float f) {
    unsigned u = __float_as_uint(f);
    unsigned r = (u + 0x7fffu + ((u >> 16) & 1u)) >> 16;
    return (unsigned short)r;
}

// Reduce NPART partials -> scalar scale t. Redundant per-wave (L2-hot 16KB).
__device__ __forceinline__ float scale_from_partials(const float* __restrict__ partials,
                                                     float invCount) {
    const int lane = threadIdx.x & 63;
    const float4* p4 = (const float4*)partials;   // NPART/4 = 1024 entries
    float s = 0.0f;
    #pragma unroll
    for (int j = 0; j < NPART / 4 / 64; ++j) {
        float4 v = p4[lane + 64 * j];
        s += v.x + v.y + v.z + v.w;
    }
    #pragma unroll
    for (int off = 32; off > 0; off >>= 1) s += __shfl_down(s, off, 64);
    s = __shfl(s, 0, 64);
    float mean = s * invCount;
    float gp = 1.0f / (mean + EPS);
    return fminf(fmaxf(rintf(gp), -1.0f), 1.0f);  // rintf = RNE = half-to-even
}

// ---- fused quantize W -> bf16 ternary + per-block |W| partial sums --------

__device__ __forceinline__ unsigned short tern_bf16(float w) {
    // +1 -> 0x3F80, -1 -> 0xBF80, 0 -> 0x0000 (exact bf16 bit patterns)
    return (w > 0.5f) ? (unsigned short)0x3F80u
         : ((w < -0.5f) ? (unsigned short)0xBF80u : (unsigned short)0u);
}

__global__ __launch_bounds__(256) void quant_w_bf16(
    const float* __restrict__ in, ushort4* __restrict__ out,
    float* __restrict__ partials, int n4)
{
    int tid = blockIdx.x * blockDim.x + threadIdx.x;
    int stride = gridDim.x * blockDim.x;
    float s = 0.0f;
    for (int i = tid; i < n4; i += stride) {
        float4 v = ((const float4*)in)[i];
        s += fabsf(v.x) + fabsf(v.y) + fabsf(v.z) + fabsf(v.w);
        ushort4 r;
        r.x = tern_bf16(v.x); r.y = tern_bf16(v.y);
        r.z = tern_bf16(v.z); r.w = tern_bf16(v.w);
        out[i] = r;
    }
    #pragma unroll
    for (int off = 32; off > 0; off >>= 1) s += __shfl_down(s, off, 64);
    __shared__ float psum[4];
    int lane = threadIdx.x & 63, wid = threadIdx.x >> 6;
    if (lane == 0) psum[wid] = s;
    __syncthreads();
    if (threadIdx.x == 0)
        partials[blockIdx.x] = psum[0] + psum[1] + psum[2] + psum[3];
}

// ---- x -> bf16 -------------------------------------------------------------

__global__ __launch_bounds__(256) void conv_x_bf16(
    const float* __restrict__ in, ushort4* __restrict__ out, int n4)
{
    int i = blockIdx.x * blockDim.x + threadIdx.x;
    if (i < n4) {
        float4 v = ((const float4*)in)[i];
        ushort4 r;
        r.x = f2bf_rne(v.x); r.y = f2bf_rne(v.y);
        r.z = f2bf_rne(v.z); r.w = f2bf_rne(v.w);
        out[i] = r;
    }
}

// ---- bf16 MFMA GEMM (B^T layout: out[m,n] = t * sum_k A[m,k]*B[n,k]) -------
// LDS layout: tile is 128 rows x 8 chunks of 16B. Chunk (row, cc) lives at
// slot row*8 + (cc ^ (row&7)). XOR swizzle keeps global_load_lds's
// "uniform base + lane*16" dest rule AND makes fragment ds_read_b128
// 2-way-max on banks (free per m136).

#define BM 128
#define BN 128
#define BK 64

__global__ __launch_bounds__(256) void gemm_bt(
    const __bf16* __restrict__ A,   // [M,K] row-major bf16
    const __bf16* __restrict__ B,   // [N,K] row-major bf16 (ternary)
    float* __restrict__ C,          // [M,N] row-major fp32
    const float* __restrict__ partials,
    int N, int K, float invCount)
{
    __shared__ __bf16 As[BM * BK];
    __shared__ __bf16 Bs[BN * BK];

    const int t    = threadIdx.x;
    const int lane = t & 63;
    const int wid  = t >> 6;
    const int mBase = blockIdx.y * BM;
    const int nBase = blockIdx.x * BN;
    const int wm = (wid >> 1) * 64;   // wave row offset in tile
    const int wn = (wid & 1) * 64;    // wave col offset in tile
    const int lm = lane & 15;
    const int quad = lane >> 4;
    const int lm7 = lm & 7;

    f32x4 acc[4][4] = {};

    const __bf16* gA = A + (size_t)mBase * K;
    const __bf16* gB = B + (size_t)nBase * K;

    for (int k0 = 0; k0 < K; k0 += BK) {
        #pragma unroll
        for (int i = 0; i < 4; ++i) {
            int ch = i * 256 + t;
            int row = ch >> 3, sc = ch & 7;
            int cc = sc ^ (row & 7);                 // source chunk for this slot
            async_load16(gA + (size_t)row * K + k0 + cc * 8, &As[ch * 8]);
        }
        #pragma unroll
        for (int i = 0; i < 4; ++i) {
            int ch = i * 256 + t;
            int row = ch >> 3, sc = ch & 7;
            int cc = sc ^ (row & 7);
            async_load16(gB + (size_t)row * K + k0 + cc * 8, &Bs[ch * 8]);
        }
        __syncthreads();   // drains vmcnt (LDS writes) + barrier

        #pragma unroll
        for (int ks = 0; ks < BK; ks += 32) {
            const int cc = (ks >> 3) + quad;         // logical chunk 0..7
            const int swz = cc ^ lm7;                // swizzled slot-in-row
            bf16x8 af[4], bfr[4];
            #pragma unroll
            for (int mt = 0; mt < 4; ++mt)
                af[mt] = *(const bf16x8*)&As[((wm + mt * 16 + lm) * 8 + swz) * 8];
            #pragma unroll
            for (int nt = 0; nt < 4; ++nt)
                bfr[nt] = *(const bf16x8*)&Bs[((wn + nt * 16 + lm) * 8 + swz) * 8];
            #pragma unroll
            for (int mt = 0; mt < 4; ++mt)
                #pragma unroll
                for (int nt = 0; nt < 4; ++nt)
                    acc[mt][nt] = __builtin_amdgcn_mfma_f32_16x16x32_bf16(
                        af[mt], bfr[nt], acc[mt][nt], 0, 0, 0);
        }
        __syncthreads();   // all reads done before next stage overwrites LDS
    }

    const float tscale = scale_from_partials(partials, invCount);

    // C/D layout: col = lane&15, row = quad*4 + reg
    #pragma unroll
    for (int mt = 0; mt < 4; ++mt) {
        #pragma unroll
        for (int nt = 0; nt < 4; ++nt) {
            #pragma unroll
            for (int r = 0; r < 4; ++r) {
                int row = mBase + wm + mt * 16 + quad * 4 + r;
                int col = nBase + wn + nt * 16 + lm;
                C[(size_t)row * N + col] = tscale * acc[mt][nt][r];
            }
        }
    }
}

// ---- fallback (ws too small): fp32 tiled GEMM with on-the-fly quantize ----

__global__ void gemm_fallback(const float* __restrict__ x, const float* __restrict__ w,
                              float* __restrict__ out, const float* __restrict__ partials,
                              int N, int K, float invCount)
{
    __shared__ float xs[16][17];
    __shared__ float qs[16][17];
    int tx = threadIdx.x & 15;
    int ty = threadIdx.x >> 4;
    int row = blockIdx.y * 16 + ty;
    int col = blockIdx.x * 16 + tx;
    float acc = 0.0f;
    for (int k0 = 0; k0 < K; k0 += 16) {
        xs[ty][tx] = x[(size_t)row * K + k0 + tx];
        float wv = w[(size_t)(blockIdx.x * 16 + ty) * K + k0 + tx];
        qs[ty][tx] = (wv > 0.5f) ? 1.0f : ((wv < -0.5f) ? -1.0f : 0.0f);
        __syncthreads();
        #pragma unroll
        for (int j = 0; j < 16; ++j) acc += xs[ty][j] * qs[tx][j];
        __syncthreads();
    }
    float tscale = scale_from_partials(partials, invCount);
    out[(size_t)row * N + col] = tscale * acc;
}

__global__ __launch_bounds__(256) void absmean_only(
    const float* __restrict__ w, float* __restrict__ partials, int n4)
{
    // used only on fallback path (no quantized output buffer)
    int tid = blockIdx.x * blockDim.x + threadIdx.x;
    int stride = gridDim.x * blockDim.x;
    float s = 0.0f;
    for (int i = tid; i < n4; i += stride) {
        float4 v = ((const float4*)w)[i];
        s += fabsf(v.x) + fabsf(v.y) + fabsf(v.z) + fabsf(v.w);
    }
    #pragma unroll
    for (int off = 32; off > 0; off >>= 1) s += __shfl_down(s, off, 64);
    __shared__ float psum[4];
    int lane = threadIdx.x & 63, wid = threadIdx.x >> 6;
    if (lane == 0) psum[wid] = s;
    __syncthreads();
    if (threadIdx.x == 0)
        partials[blockIdx.x] = psum[0] + psum[1] + psum[2] + psum[3];
}

// ---------------------------------------------------------------------------

extern "C" void kernel_launch(void* const* d_in, const int* in_sizes, int n_in,
                              void* d_out, int out_size, void* d_ws, size_t ws_size,
                              hipStream_t stream) {
    const float* x = (const float*)d_in[0];
    const float* w = (const float*)d_in[1];
    float* out = (float*)d_out;

    const int K = 4096;
    const int M = in_sizes[0] / K;       // 8192
    const int N = in_sizes[1] / K;       // 4096
    const float invCount = 1.0f / (float)(in_sizes[1]);

    float* partials = (float*)d_ws;                       // NPART floats = 16 KB
    const size_t base = NPART * sizeof(float);
    const size_t need = base + (size_t)M * K * 2 + (size_t)N * K * 2;

    if (ws_size >= need) {
        __bf16* xb = (__bf16*)((char*)d_ws + base);
        __bf16* qb = (__bf16*)((char*)d_ws + base + (size_t)M * K * 2);

        int xn4 = (M * K) / 4;
        int wn4 = (N * K) / 4;
        quant_w_bf16<<<NPART, 256, 0, stream>>>(w, (ushort4*)qb, partials, wn4);
        conv_x_bf16<<<(xn4 + 255) / 256, 256, 0, stream>>>(x, (ushort4*)xb, xn4);

        dim3 grid(N / BN, M / BM);
        gemm_bt<<<grid, 256, 0, stream>>>(xb, qb, out, partials, N, K, invCount);
    } else {
        absmean_only<<<NPART, 256, 0, stream>>>(w, partials, in_sizes[1] / 4);
        dim3 grid(N / 16, M / 16);
        gemm_fallback<<<grid, 256, 0, stream>>>(x, w, out, partials, N, K, invCount);
    }
}